// Round 4
// baseline (562.650 us; speedup 1.0000x reference)
//
#include <hip/hip_runtime.h>

// WindowAttention: B=256 windows, N=256 tokens, C=384, 12 heads, d=32.
// Pipeline: K0 cast weights->bf16 | K1 transpose-cast x (B,C,N)f32 -> xt (B*N,C)bf16
//           K2 per-(b,h): qkv MFMA GEMM + l2norm + MFMA attention -> attn (B*N,C)bf16
//           K3 proj GEMM + output transpose -> (B,C,N) f32
// MFMA 16x16x32 bf16 layouts (verified m89/m91/m120):
//   A: A[m][k] m=lane&15, k=(lane>>4)*8+j ; B: B[k][n] n=lane&15, k=(lane>>4)*8+j
//   D: col=lane&15, row=(lane>>4)*4+r
// Softmax: logits in [-0.178,0.178] -> no max-subtract; clip(1e-6,1) no-op.
// SCALE/ln2 folded into qhat so p = exp2(s).
// R4 changes vs R3 (533us: launch_bounds(256,4) forced 128-reg budget -> ~650MB/disp
// scratch spill traffic, FETCH 245MB WRITE 463MB):
//  (a) token-half split in K2 phase A and K3: acc[6][4] -> 2 passes of acc[6][2]
//      (96 -> 48 AGPRs peak). Register demand ~150 fits launch_bounds(256,3)'s
//      ~170 budget WITHOUT spills; LDS 37.8KB allows it -> 3 blocks/CU for real.
//  (b) keep R3 wins: zero-shuffle PV (P in registers), qa via bpermute, no qn/pbuf.

#define DIM 384
#define NT 256
#define NH 12
#define HD 32
#define QSCALE (0.17677669529663687f * 1.4426950408889634f)  // SCALE/ln2

typedef __bf16 bf16;
typedef __bf16 bf16x2 __attribute__((ext_vector_type(2)));
typedef __bf16 bf16x4 __attribute__((ext_vector_type(4)));
typedef __bf16 bf16x8 __attribute__((ext_vector_type(8)));
typedef float f32x4 __attribute__((ext_vector_type(4)));
typedef int i32x4 __attribute__((ext_vector_type(4)));

#define MFMA16(a, b, c) __builtin_amdgcn_mfma_f32_16x16x32_bf16(a, b, c, 0, 0, 0)

// ---------------- K0: cast weights to bf16 ----------------
__global__ void k_cast_w(const float* __restrict__ qkv_w, const float* __restrict__ proj_w,
                         bf16* __restrict__ wq, bf16* __restrict__ wp) {
    int i = blockIdx.x * 256 + threadIdx.x;
    if (i < 3 * DIM * DIM) wq[i] = (bf16)qkv_w[i];
    if (i < DIM * DIM)     wp[i] = (bf16)proj_w[i];
}

// ---------------- K1: x (B,C,N) f32 -> xt (B*N, C) bf16 ----------------
__global__ void k_transpose_cast(const float* __restrict__ x, bf16* __restrict__ xt) {
    __shared__ float tile[32][33];
    int b = blockIdx.z;
    int c0 = blockIdx.y * 32;
    int n0 = blockIdx.x * 32;
    int tx = threadIdx.x, ty = threadIdx.y;
    const float* xp = x + (size_t)b * DIM * NT;
#pragma unroll
    for (int i = 0; i < 4; ++i) {
        int c = c0 + ty + i * 8;
        tile[ty + i * 8][tx] = xp[(size_t)c * NT + n0 + tx];
    }
    __syncthreads();
    bf16* op = xt + (size_t)b * NT * DIM;
#pragma unroll
    for (int i = 0; i < 4; ++i) {
        int n = n0 + ty + i * 8;
        op[(size_t)n * DIM + c0 + tx] = (bf16)tile[tx][ty + i * 8];
    }
}

// ---------------- K2: fused qkv GEMM + l2norm + attention, one block per (b,h) ----------------
__launch_bounds__(256, 3)
__global__ void k_qkv_attn(const bf16* __restrict__ xt, const bf16* __restrict__ wq,
                           const float* __restrict__ qkv_b, bf16* __restrict__ attn_out) {
    // LDS: kn 20480 + vT 16896 + bias 384 = 37760 B (4-block capable; regs cap at 3)
    __shared__ bf16 kn[NT][40];       // normalized k, row pad 40 (80B)
    __shared__ bf16 vT[HD][264];      // v transposed [d][token], pad 264 (528B)
    __shared__ float bias_s[96];

    // XCD-pinned decode: all 12 head-blocks of a batch share one XCD/L2.
    const int n_ = blockIdx.x;            // grid = 3072 (bijective remap of (h,b))
    const int xcd = n_ & 7;
    const int ww = n_ >> 3;               // 0..383
    const int b = xcd * 32 + ww / 12;
    const int h = ww % 12;

    const int tid = threadIdx.x;
    const int lane = tid & 63, w = tid >> 6;
    const int l15 = lane & 15, quad = lane >> 4;

    if (tid < 96) {
        int which = tid >> 5;
        bias_s[tid] = qkv_b[which * DIM + h * HD + (tid & 31)];
    }
    __syncthreads();

    // ---- Phase A: qkv GEMM in two token-halves (acc[6][2] = 48 AGPRs peak).
    // Wave w owns tokens [w*64, w*64+64); half hh covers [w*64+hh*32, +32).
    bf16x8 qa[4];                                      // Q B-frags for qt=0..3
    const int addr0 = (((2 * quad) & 3) * 16 + l15) * 4;       // bperm byte addr
    const int addr1 = (((2 * quad + 1) & 3) * 16 + l15) * 4;

    const bf16* wrow[6];
#pragma unroll
    for (int jt = 0; jt < 6; ++jt) {
        int jj = jt * 16 + l15;
        int which = jj >> 5;
        wrow[jt] = wq + (size_t)(which * DIM + h * HD + (jj & 31)) * DIM + quad * 8;
    }

#pragma unroll 1
    for (int hh = 0; hh < 2; ++hh) {
        f32x4 acc[6][2];
#pragma unroll
        for (int jt = 0; jt < 6; ++jt)
#pragma unroll
            for (int tt = 0; tt < 2; ++tt) acc[jt][tt] = (f32x4){0.f, 0.f, 0.f, 0.f};

        const bf16* xrow[2];
#pragma unroll
        for (int tt = 0; tt < 2; ++tt) {
            int tok = w * 64 + (hh * 2 + tt) * 16 + l15;
            xrow[tt] = xt + (size_t)(b * NT + tok) * DIM + quad * 8;
        }

#pragma unroll 2
        for (int kc = 0; kc < 12; ++kc) {
            int k0 = kc * 32;
            bf16x8 bfr[2], afr[6];
#pragma unroll
            for (int tt = 0; tt < 2; ++tt) bfr[tt] = *(const bf16x8*)(xrow[tt] + k0);
#pragma unroll
            for (int jt = 0; jt < 6; ++jt) afr[jt] = *(const bf16x8*)(wrow[jt] + k0);
#pragma unroll
            for (int jt = 0; jt < 6; ++jt)
#pragma unroll
                for (int tt = 0; tt < 2; ++tt)
                    acc[jt][tt] = MFMA16(afr[jt], bfr[tt], acc[jt][tt]);
        }

        // ---- epilogue: +bias, l2-normalize q,k; q -> registers (bpermute exchange),
        //      k -> kn (2x b64 stores), v -> vT.
#pragma unroll
        for (int tt = 0; tt < 2; ++tt) {
            int ti = hh * 2 + tt;              // global tt index 0..3
            int tok = w * 64 + ti * 16 + l15;  // = D col for this frag
            float sq = 0.f, sk = 0.f;
#pragma unroll
            for (int jt = 0; jt < 6; ++jt)
#pragma unroll
                for (int r = 0; r < 4; ++r) {
                    int j = jt * 16 + quad * 4 + r;  // D row
                    float t = acc[jt][tt][r] + bias_s[j];
                    acc[jt][tt][r] = t;
                    if (jt < 2) sq += t * t;
                    else if (jt < 4) sk += t * t;
                }
            sq += __shfl_xor(sq, 16); sq += __shfl_xor(sq, 32);
            sk += __shfl_xor(sk, 16); sk += __shfl_xor(sk, 32);
            float iq = QSCALE / fmaxf(sqrtf(sq), 1e-12f);
            float ik = 1.f / fmaxf(sqrtf(sk), 1e-12f);

            // --- q: lane holds qhat dims {4*quad+r} (acc[0]) and {16+4*quad+r} (acc[1]).
            // Dest lane (q,l15) wants dims 8q..8q+7 of the same token. Pack pairs, pull
            // from source quad (2q)&3 / (2q+1)&3, select lo/hi pack by dest quad.
            bf16x2 pkA, pkB, pkC, pkD;
            pkA[0] = (bf16)(acc[0][tt][0] * iq); pkA[1] = (bf16)(acc[0][tt][1] * iq);
            pkB[0] = (bf16)(acc[0][tt][2] * iq); pkB[1] = (bf16)(acc[0][tt][3] * iq);
            pkC[0] = (bf16)(acc[1][tt][0] * iq); pkC[1] = (bf16)(acc[1][tt][1] * iq);
            pkD[0] = (bf16)(acc[1][tt][2] * iq); pkD[1] = (bf16)(acc[1][tt][3] * iq);
            int iA = __builtin_bit_cast(int, pkA), iB = __builtin_bit_cast(int, pkB);
            int iC = __builtin_bit_cast(int, pkC), iD = __builtin_bit_cast(int, pkD);
            int a0A = __builtin_amdgcn_ds_bpermute(addr0, iA);
            int a0C = __builtin_amdgcn_ds_bpermute(addr0, iC);
            int a0B = __builtin_amdgcn_ds_bpermute(addr0, iB);
            int a0D = __builtin_amdgcn_ds_bpermute(addr0, iD);
            int a1A = __builtin_amdgcn_ds_bpermute(addr1, iA);
            int a1C = __builtin_amdgcn_ds_bpermute(addr1, iC);
            int a1B = __builtin_amdgcn_ds_bpermute(addr1, iB);
            int a1D = __builtin_amdgcn_ds_bpermute(addr1, iD);
            bool lo = quad < 2;
            i32x4 qi = {lo ? a0A : a0C, lo ? a0B : a0D, lo ? a1A : a1C, lo ? a1B : a1D};
            qa[ti] = __builtin_bit_cast(bf16x8, qi);

            // --- k: vectorized b64 stores
            bf16x4 k0v, k1v;
#pragma unroll
            for (int r = 0; r < 4; ++r) {
                k0v[r] = (bf16)(acc[2][tt][r] * ik);
                k1v[r] = (bf16)(acc[3][tt][r] * ik);
            }
            *(bf16x4*)&kn[tok][quad * 4]      = k0v;
            *(bf16x4*)&kn[tok][16 + quad * 4] = k1v;

            // --- v: column-major scatter (scalar b16)
#pragma unroll
            for (int r = 0; r < 4; ++r) {
                vT[quad * 4 + r][tok]      = (bf16)acc[4][tt][r];
                vT[16 + quad * 4 + r][tok] = (bf16)acc[5][tt][r];
            }
        }
    }
    __syncthreads();

    // ---- Phase C: attention, kt-outer / qt-inner, P fully in registers.
    // k-slot permutation: slot 8q+j <-> token nk0+4q+j (j<4), nk0+16+4q+(j-4) (j>=4);
    // applied identically to pa and vb so the PV product is unchanged.
    const f32x4 zf = {0.f, 0.f, 0.f, 0.f};
    f32x4 o[4][2];
#pragma unroll
    for (int qt = 0; qt < 4; ++qt) { o[qt][0] = zf; o[qt][1] = zf; }
    float dsm[4] = {0.f, 0.f, 0.f, 0.f};

#pragma unroll 1
    for (int kt = 0; kt < 8; ++kt) {  // 32 keys per chunk
        int nk0 = kt * 32;
        // K A-frags (b128) + V B-frags (2x b64 each, permuted token runs)
        bf16x8 kb0 = *(const bf16x8*)&kn[nk0 + l15][quad * 8];
        bf16x8 kb1 = *(const bf16x8*)&kn[nk0 + 16 + l15][quad * 8];
        bf16x4 v0lo = *(const bf16x4*)&vT[l15][nk0 + quad * 4];
        bf16x4 v0hi = *(const bf16x4*)&vT[l15][nk0 + 16 + quad * 4];
        bf16x4 v1lo = *(const bf16x4*)&vT[16 + l15][nk0 + quad * 4];
        bf16x4 v1hi = *(const bf16x4*)&vT[16 + l15][nk0 + 16 + quad * 4];
        bf16x8 vb0, vb1;
#pragma unroll
        for (int j = 0; j < 4; ++j) {
            vb0[j] = v0lo[j]; vb0[4 + j] = v0hi[j];
            vb1[j] = v1lo[j]; vb1[4 + j] = v1hi[j];
        }

        // S^T = MFMA(K, Q): lane (q,l15) gets keys nk0+4q+r (s0) / nk0+16+4q+r (s1)
        // at query qt*16+l15 -> exactly this lane's pa slots 0..3 / 4..7.
        f32x4 s0 = MFMA16(kb0, qa[0], zf);
        f32x4 s1 = MFMA16(kb1, qa[0], zf);
#pragma unroll
        for (int qt = 0; qt < 4; ++qt) {
            bf16x8 pa;
            float d0 = 0.f;
#pragma unroll
            for (int r = 0; r < 4; ++r) {
                float p0 = __builtin_amdgcn_exp2f(s0[r]);
                float p1 = __builtin_amdgcn_exp2f(s1[r]);
                d0 += p0 + p1;
                pa[r]     = (bf16)p0;
                pa[4 + r] = (bf16)p1;
            }
            dsm[qt] += d0;
            // prefetch next qt's S while exp/cvt retire
            if (qt < 3) {
                s0 = MFMA16(kb0, qa[qt + 1], zf);
                s1 = MFMA16(kb1, qa[qt + 1], zf);
            }
            o[qt][0] = MFMA16(pa, vb0, o[qt][0]);
            o[qt][1] = MFMA16(pa, vb1, o[qt][1]);
        }
    }

    // denom: reduce per-lane partials over the 4 quads -> full denom for query base+l15
#pragma unroll
    for (int qt = 0; qt < 4; ++qt) {
        dsm[qt] += __shfl_xor(dsm[qt], 16);
        dsm[qt] += __shfl_xor(dsm[qt], 32);
    }
    bf16* opbase = attn_out + (size_t)(b * NT + w * 64) * DIM + h * HD;
#pragma unroll
    for (int qt = 0; qt < 4; ++qt)
#pragma unroll
        for (int r = 0; r < 4; ++r) {
            // O row = query quad*4+r; its denom lives at lane l15 == quad*4+r
            float inv = 1.f / __shfl(dsm[qt], quad * 4 + r);
            int nq = qt * 16 + quad * 4 + r;
            opbase[(size_t)nq * DIM + l15]      = (bf16)(o[qt][0][r] * inv);
            opbase[(size_t)nq * DIM + 16 + l15] = (bf16)(o[qt][1][r] * inv);
        }
}

// ---------------- K3: proj GEMM + output transpose (token-half split) ----------------
__launch_bounds__(256, 3)
__global__ void k_proj(const bf16* __restrict__ xa, const bf16* __restrict__ wp,
                       const float* __restrict__ proj_b, float* __restrict__ out) {
    __shared__ float bias_s[96];
    // XCD-pinned decode (grid = 1024): 4 cb-blocks of a batch share one L2.
    const int n_ = blockIdx.x;
    const int xcd = n_ & 7;
    const int ww = n_ >> 3;               // 0..127
    const int b  = xcd * 32 + (ww >> 2);
    const int cb = ww & 3;                // 96-wide slice of 384 out channels

    const int tid = threadIdx.x;
    const int lane = tid & 63, w = tid >> 6;
    const int l15 = lane & 15, quad = lane >> 4;
    if (tid < 96) bias_s[tid] = proj_b[cb * 96 + tid];
    __syncthreads();

    const bf16* arow[6];
#pragma unroll
    for (int jt = 0; jt < 6; ++jt)
        arow[jt] = wp + (size_t)(cb * 96 + jt * 16 + l15) * DIM + quad * 8;

    float* op = out + (size_t)b * DIM * NT;  // out[b][c][n]

#pragma unroll 1
    for (int hh = 0; hh < 2; ++hh) {
        f32x4 acc[6][2];
#pragma unroll
        for (int jt = 0; jt < 6; ++jt)
#pragma unroll
            for (int tt = 0; tt < 2; ++tt) acc[jt][tt] = (f32x4){0.f, 0.f, 0.f, 0.f};

        const bf16* brow[2];
#pragma unroll
        for (int tt = 0; tt < 2; ++tt)
            brow[tt] = xa + (size_t)(b * NT + w * 64 + (hh * 2 + tt) * 16 + l15) * DIM + quad * 8;

#pragma unroll 2
        for (int kc = 0; kc < 12; ++kc) {
            int k0 = kc * 32;
            bf16x8 bfr[2], afr[6];
#pragma unroll
            for (int tt = 0; tt < 2; ++tt) bfr[tt] = *(const bf16x8*)(brow[tt] + k0);
#pragma unroll
            for (int jt = 0; jt < 6; ++jt) afr[jt] = *(const bf16x8*)(arow[jt] + k0);
#pragma unroll
            for (int jt = 0; jt < 6; ++jt)
#pragma unroll
                for (int tt = 0; tt < 2; ++tt)
                    acc[jt][tt] = MFMA16(afr[jt], bfr[tt], acc[jt][tt]);
        }

#pragma unroll
        for (int jt = 0; jt < 6; ++jt)
#pragma unroll
            for (int tt = 0; tt < 2; ++tt)
#pragma unroll
                for (int r = 0; r < 4; ++r) {
                    int cl = jt * 16 + quad * 4 + r;                // D row = out channel
                    int n  = w * 64 + (hh * 2 + tt) * 16 + l15;    // D col = token
                    op[(size_t)(cb * 96 + cl) * NT + n] = acc[jt][tt][r] + bias_s[cl];
                }
    }
}

extern "C" void kernel_launch(void* const* d_in, const int* in_sizes, int n_in,
                              void* d_out, int out_size, void* d_ws, size_t ws_size,
                              hipStream_t stream) {
    const float* x      = (const float*)d_in[0];
    const float* qkv_w  = (const float*)d_in[1];
    const float* qkv_b  = (const float*)d_in[2];
    const float* proj_w = (const float*)d_in[3];
    const float* proj_b = (const float*)d_in[4];
    float* out = (float*)d_out;

    char* ws = (char*)d_ws;
    bf16* xt = (bf16*)ws;                    // 256*256*384*2 = 50,331,648 B
    bf16* xa = (bf16*)(ws + 50331648);       // 50,331,648 B
    bf16* wq = (bf16*)(ws + 100663296);      // 884,736 B
    bf16* wp = (bf16*)(ws + 101548032);      // 294,912 B  (total 101,842,944 B)

    k_cast_w<<<dim3(1728), dim3(256), 0, stream>>>(qkv_w, proj_w, wq, wp);
    k_transpose_cast<<<dim3(8, 12, 256), dim3(32, 8), 0, stream>>>(x, xt);
    k_qkv_attn<<<dim3(NH * 256), dim3(256), 0, stream>>>(xt, wq, qkv_b, xa);
    k_proj<<<dim3(4 * 256), dim3(256), 0, stream>>>(xa, wp, proj_b, out);
}

// Round 6
// 490.627 us; speedup vs baseline: 1.1468x; 1.1468x over previous
//
#include <hip/hip_runtime.h>

// WindowAttention: B=256 windows, N=256 tokens, C=384, 12 heads, d=32.
// Pipeline: K0 cast weights->bf16
//           K2 per-(b,h): qkv MFMA GEMM (direct from x) + l2norm + MFMA attention -> xa bf16
//           K3 proj MFMA GEMM (48-ch tiles) + output transpose -> (B,C,N) f32
// MFMA 16x16x32 bf16 layouts (verified m89/m91/m120):
//   A: A[m][k] m=lane&15, k=(lane>>4)*8+j ; B: B[k][n] n=lane&15, k=(lane>>4)*8+j
//   D: col=lane&15, row=(lane>>4)*4+r
// Softmax: logits in [-0.178,0.178] -> no max-subtract; clip(1e-6,1) no-op.
// SCALE/ln2 folded into qhat so p = exp2(s).
// R5 changes vs R4 (563us; K2=309, VALU-work bloat + only 3 blk/CU; K0+K1+K3~225us):
//  (a) K2 512-thr blocks, 8 waves x 32 tokens: acc[6][2]=48 regs PARALLEL (not R4's
//      serial split) -> fits launch_bounds(512,4)=128 regs -> 16 waves/CU (4/SIMD).
//  (b) K1 deleted: phase A reads x (B,C,N) f32 directly as B-frags (8 stride-N
//      scalar loads/lane, 64B-coalesced, L2-hot under XCD pinning). -100MB traffic.
//  (c) zero-VALU packing: vb/pa via dword bit_cast; q via small qn LDS (2 b64
//      stores) instead of 32 ds_bpermute.
//  (d) K3: 48-channel tiles, acc[3][4], launch_bounds(256,4) -> 4 blk/CU, grid 2048.
// (R6 = R5 resubmitted: GPU acquisition timed out, kernel never ran.)

#define DIM 384
#define NT 256
#define NH 12
#define HD 32
#define QSCALE (0.17677669529663687f * 1.4426950408889634f)  // SCALE/ln2

typedef __bf16 bf16;
typedef __bf16 bf16x4 __attribute__((ext_vector_type(4)));
typedef __bf16 bf16x8 __attribute__((ext_vector_type(8)));
typedef float f32x4 __attribute__((ext_vector_type(4)));
typedef int i32x2 __attribute__((ext_vector_type(2)));
typedef int i32x4 __attribute__((ext_vector_type(4)));

#define MFMA16(a, b, c) __builtin_amdgcn_mfma_f32_16x16x32_bf16(a, b, c, 0, 0, 0)

// zero-VALU: combine two bf16x4 (2 VGPRs each) into a bf16x8 by register renaming
static __device__ __forceinline__ bf16x8 pack2(bf16x4 lo, bf16x4 hi) {
    i32x2 a = __builtin_bit_cast(i32x2, lo);
    i32x2 c = __builtin_bit_cast(i32x2, hi);
    i32x4 v = {a[0], a[1], c[0], c[1]};
    return __builtin_bit_cast(bf16x8, v);
}

// ---------------- K0: cast weights to bf16 ----------------
__global__ void k_cast_w(const float* __restrict__ qkv_w, const float* __restrict__ proj_w,
                         bf16* __restrict__ wq, bf16* __restrict__ wp) {
    int i = blockIdx.x * 256 + threadIdx.x;
    if (i < 3 * DIM * DIM) wq[i] = (bf16)qkv_w[i];
    if (i < DIM * DIM)     wp[i] = (bf16)proj_w[i];
}

// ---------------- K2: fused qkv GEMM + l2norm + attention, one block per (b,h) ----------------
__launch_bounds__(512, 4)
__global__ void k_qkv_attn(const float* __restrict__ x, const bf16* __restrict__ wq,
                           const float* __restrict__ qkv_b, bf16* __restrict__ attn_out) {
    // LDS: kn 20480 + vT 16896 + qn 16384 + bias 384 = 54144 B -> 2 blocks/CU (512thr)
    __shared__ bf16 kn[NT][40];       // normalized k, row pad 40 (80B)
    __shared__ bf16 vT[HD][264];      // v transposed [d][token], pad 264 (528B)
    __shared__ bf16 qn[NT][32];       // normalized q*QSCALE
    __shared__ float bias_s[96];

    // XCD-pinned decode: all 12 head-blocks of a batch share one XCD/L2.
    const int n_ = blockIdx.x;            // grid = 3072 (bijective remap of (h,b))
    const int xcd = n_ & 7;
    const int ww = n_ >> 3;               // 0..383
    const int b = xcd * 32 + ww / 12;
    const int h = ww % 12;

    const int tid = threadIdx.x;
    const int lane = tid & 63, w = tid >> 6;   // w = 0..7
    const int l15 = lane & 15, quad = lane >> 4;

    if (tid < 96) {
        int which = tid >> 5;
        bias_s[tid] = qkv_b[which * DIM + h * HD + (tid & 31)];
    }
    __syncthreads();

    // ---- Phase A: qkv GEMM. Wave w owns tokens [w*32, w*32+32) (2 frags of 16).
    // B-frag read DIRECTLY from x[b][c][tok] f32: lane (quad,l15) loads 8 values at
    // stride NT (each a 64B-coalesced segment across the 16 l15 lanes), cvt to bf16.
    f32x4 acc[6][2];
#pragma unroll
    for (int jt = 0; jt < 6; ++jt)
#pragma unroll
        for (int tt = 0; tt < 2; ++tt) acc[jt][tt] = (f32x4){0.f, 0.f, 0.f, 0.f};

    const float* xbase = x + (size_t)b * DIM * NT;
    const bf16* wrow[6];
#pragma unroll
    for (int jt = 0; jt < 6; ++jt) {
        int jj = jt * 16 + l15;
        int which = jj >> 5;
        wrow[jt] = wq + (size_t)(which * DIM + h * HD + (jj & 31)) * DIM + quad * 8;
    }

#pragma unroll 2
    for (int kc = 0; kc < 12; ++kc) {
        int k0c = kc * 32;
        bf16x8 afr[6], bfr[2];
#pragma unroll
        for (int tt = 0; tt < 2; ++tt) {
            const float* xp = xbase + (size_t)(k0c + quad * 8) * NT + w * 32 + tt * 16 + l15;
            float f0 = xp[0 * NT], f1 = xp[1 * NT], f2 = xp[2 * NT], f3 = xp[3 * NT];
            float f4 = xp[4 * NT], f5 = xp[5 * NT], f6 = xp[6 * NT], f7 = xp[7 * NT];
            bfr[tt][0] = (bf16)f0; bfr[tt][1] = (bf16)f1;
            bfr[tt][2] = (bf16)f2; bfr[tt][3] = (bf16)f3;
            bfr[tt][4] = (bf16)f4; bfr[tt][5] = (bf16)f5;
            bfr[tt][6] = (bf16)f6; bfr[tt][7] = (bf16)f7;
        }
#pragma unroll
        for (int jt = 0; jt < 6; ++jt) afr[jt] = *(const bf16x8*)(wrow[jt] + k0c);
#pragma unroll
        for (int jt = 0; jt < 6; ++jt)
#pragma unroll
            for (int tt = 0; tt < 2; ++tt)
                acc[jt][tt] = MFMA16(afr[jt], bfr[tt], acc[jt][tt]);
    }

    // ---- epilogue: +bias, l2-normalize q,k; q->qn, k->kn (b64 stores), v->vT.
#pragma unroll
    for (int tt = 0; tt < 2; ++tt) {
        int tok = w * 32 + tt * 16 + l15;  // = D col for this frag
        float sq = 0.f, sk = 0.f;
#pragma unroll
        for (int jt = 0; jt < 6; ++jt)
#pragma unroll
            for (int r = 0; r < 4; ++r) {
                int j = jt * 16 + quad * 4 + r;  // D row
                float t = acc[jt][tt][r] + bias_s[j];
                acc[jt][tt][r] = t;
                if (jt < 2) sq += t * t;
                else if (jt < 4) sk += t * t;
            }
        sq += __shfl_xor(sq, 16); sq += __shfl_xor(sq, 32);
        sk += __shfl_xor(sk, 16); sk += __shfl_xor(sk, 32);
        float iq = QSCALE / fmaxf(sqrtf(sq), 1e-12f);
        float ik = 1.f / fmaxf(sqrtf(sk), 1e-12f);

        bf16x4 q0v, q1v, k0v, k1v;
#pragma unroll
        for (int r = 0; r < 4; ++r) {
            q0v[r] = (bf16)(acc[0][tt][r] * iq);
            q1v[r] = (bf16)(acc[1][tt][r] * iq);
            k0v[r] = (bf16)(acc[2][tt][r] * ik);
            k1v[r] = (bf16)(acc[3][tt][r] * ik);
        }
        *(bf16x4*)&qn[tok][quad * 4]      = q0v;
        *(bf16x4*)&qn[tok][16 + quad * 4] = q1v;
        *(bf16x4*)&kn[tok][quad * 4]      = k0v;
        *(bf16x4*)&kn[tok][16 + quad * 4] = k1v;
#pragma unroll
        for (int r = 0; r < 4; ++r) {
            vT[quad * 4 + r][tok]      = (bf16)acc[4][tt][r];
            vT[16 + quad * 4 + r][tok] = (bf16)acc[5][tt][r];
        }
    }
    __syncthreads();

    // ---- Phase C: attention, kt-outer / qt-inner, P fully in registers.
    // k-slot permutation: slot 8q+j <-> token nk0+4q+j (j<4), nk0+16+4q+(j-4) (j>=4);
    // applied identically to pa and vb so the PV product is unchanged.
    bf16x8 qa[2];
#pragma unroll
    for (int qt = 0; qt < 2; ++qt)
        qa[qt] = *(const bf16x8*)&qn[w * 32 + qt * 16 + l15][quad * 8];

    const f32x4 zf = {0.f, 0.f, 0.f, 0.f};
    f32x4 o[2][2];
#pragma unroll
    for (int qt = 0; qt < 2; ++qt) { o[qt][0] = zf; o[qt][1] = zf; }
    float dsm[2] = {0.f, 0.f};

#pragma unroll 1
    for (int kt = 0; kt < 8; ++kt) {  // 32 keys per chunk
        int nk0 = kt * 32;
        // K A-frags (b128) + V B-frags (4x b64, combined by register renaming)
        bf16x8 kb0 = *(const bf16x8*)&kn[nk0 + l15][quad * 8];
        bf16x8 kb1 = *(const bf16x8*)&kn[nk0 + 16 + l15][quad * 8];
        bf16x8 vb0 = pack2(*(const bf16x4*)&vT[l15][nk0 + quad * 4],
                           *(const bf16x4*)&vT[l15][nk0 + 16 + quad * 4]);
        bf16x8 vb1 = pack2(*(const bf16x4*)&vT[16 + l15][nk0 + quad * 4],
                           *(const bf16x4*)&vT[16 + l15][nk0 + 16 + quad * 4]);

        // S^T = MFMA(K, Q): lane (q,l15) gets keys nk0+4q+r (s0) / nk0+16+4q+r (s1)
        // at query qbase+qt*16+l15 -> exactly this lane's pa slots 0..3 / 4..7.
        f32x4 s0 = MFMA16(kb0, qa[0], zf);
        f32x4 s1 = MFMA16(kb1, qa[0], zf);
#pragma unroll
        for (int qt = 0; qt < 2; ++qt) {
            bf16x8 pa;
            float d0 = 0.f;
#pragma unroll
            for (int r = 0; r < 4; ++r) {
                float p0 = __builtin_amdgcn_exp2f(s0[r]);
                float p1 = __builtin_amdgcn_exp2f(s1[r]);
                d0 += p0 + p1;
                pa[r]     = (bf16)p0;   // adjacent pairs -> v_cvt_pk_bf16_f32
                pa[4 + r] = (bf16)p1;
            }
            dsm[qt] += d0;
            if (qt < 1) {  // prefetch next qt's S while exp/cvt retire
                s0 = MFMA16(kb0, qa[1], zf);
                s1 = MFMA16(kb1, qa[1], zf);
            }
            o[qt][0] = MFMA16(pa, vb0, o[qt][0]);
            o[qt][1] = MFMA16(pa, vb1, o[qt][1]);
        }
    }

    // denom: reduce per-lane partials over the 4 quads -> full denom at lanes <16
#pragma unroll
    for (int qt = 0; qt < 2; ++qt) {
        dsm[qt] += __shfl_xor(dsm[qt], 16);
        dsm[qt] += __shfl_xor(dsm[qt], 32);
    }
    bf16* opbase = attn_out + (size_t)(b * NT + w * 32) * DIM + h * HD;
#pragma unroll
    for (int qt = 0; qt < 2; ++qt)
#pragma unroll
        for (int r = 0; r < 4; ++r) {
            // O row = query quad*4+r; its denom lives at lane l15 == quad*4+r
            float inv = 1.f / __shfl(dsm[qt], quad * 4 + r);
            int nq = qt * 16 + quad * 4 + r;
            opbase[(size_t)nq * DIM + l15]      = (bf16)(o[qt][0][r] * inv);
            opbase[(size_t)nq * DIM + 16 + l15] = (bf16)(o[qt][1][r] * inv);
        }
}

// ---------------- K3: proj GEMM (48-ch tiles) + output transpose ----------------
__launch_bounds__(256, 4)
__global__ void k_proj(const bf16* __restrict__ xa, const bf16* __restrict__ wp,
                       const float* __restrict__ proj_b, float* __restrict__ out) {
    __shared__ float bias_s[48];
    // XCD-pinned decode (grid = 2048): 8 cb-slices of a batch share one L2.
    const int n_ = blockIdx.x;
    const int xcd = n_ & 7;
    const int ww = n_ >> 3;               // 0..255
    const int b  = xcd * 32 + (ww >> 3);
    const int cb = ww & 7;                // 48-wide slice of 384 out channels

    const int tid = threadIdx.x;
    const int lane = tid & 63, w = tid >> 6;
    const int l15 = lane & 15, quad = lane >> 4;
    if (tid < 48) bias_s[tid] = proj_b[cb * 48 + tid];
    __syncthreads();

    f32x4 acc[3][4];
#pragma unroll
    for (int jt = 0; jt < 3; ++jt)
#pragma unroll
        for (int tt = 0; tt < 4; ++tt) acc[jt][tt] = (f32x4){0.f, 0.f, 0.f, 0.f};

    const bf16* arow[3];
#pragma unroll
    for (int jt = 0; jt < 3; ++jt)
        arow[jt] = wp + (size_t)(cb * 48 + jt * 16 + l15) * DIM + quad * 8;
    const bf16* brow[4];
#pragma unroll
    for (int tt = 0; tt < 4; ++tt)
        brow[tt] = xa + (size_t)(b * NT + w * 64 + tt * 16 + l15) * DIM + quad * 8;

#pragma unroll 2
    for (int kc = 0; kc < 12; ++kc) {
        int k0 = kc * 32;
        bf16x8 bfr[4], afr[3];
#pragma unroll
        for (int tt = 0; tt < 4; ++tt) bfr[tt] = *(const bf16x8*)(brow[tt] + k0);
#pragma unroll
        for (int jt = 0; jt < 3; ++jt) afr[jt] = *(const bf16x8*)(arow[jt] + k0);
#pragma unroll
        for (int jt = 0; jt < 3; ++jt)
#pragma unroll
            for (int tt = 0; tt < 4; ++tt)
                acc[jt][tt] = MFMA16(afr[jt], bfr[tt], acc[jt][tt]);
    }

    float* op = out + (size_t)b * DIM * NT;  // out[b][c][n]
#pragma unroll
    for (int jt = 0; jt < 3; ++jt)
#pragma unroll
        for (int tt = 0; tt < 4; ++tt)
#pragma unroll
            for (int r = 0; r < 4; ++r) {
                int cl = jt * 16 + quad * 4 + r;          // D row = out channel (local)
                int n  = w * 64 + tt * 16 + l15;          // D col = token
                op[(size_t)(cb * 48 + cl) * NT + n] = acc[jt][tt][r] + bias_s[cl];
            }
}

extern "C" void kernel_launch(void* const* d_in, const int* in_sizes, int n_in,
                              void* d_out, int out_size, void* d_ws, size_t ws_size,
                              hipStream_t stream) {
    const float* x      = (const float*)d_in[0];
    const float* qkv_w  = (const float*)d_in[1];
    const float* qkv_b  = (const float*)d_in[2];
    const float* proj_w = (const float*)d_in[3];
    const float* proj_b = (const float*)d_in[4];
    float* out = (float*)d_out;

    char* ws = (char*)d_ws;
    bf16* xa = (bf16*)ws;                    // 256*256*384*2 = 50,331,648 B
    bf16* wq = (bf16*)(ws + 50331648);       // 884,736 B
    bf16* wp = (bf16*)(ws + 51216384);       // 294,912 B  (total 51,511,296 B)

    k_cast_w<<<dim3(1728), dim3(256), 0, stream>>>(qkv_w, proj_w, wq, wp);
    k_qkv_attn<<<dim3(NH * 256), dim3(512), 0, stream>>>(x, wq, qkv_b, xa);
    k_proj<<<dim3(8 * 256), dim3(256), 0, stream>>>(xa, wp, proj_b, out);
}